// Round 11
// baseline (366.038 us; speedup 1.0000x reference)
//
#include <hip/hip_runtime.h>
#include <math.h>

namespace {
constexpr int CDIM   = 128;
constexpr int KCODES = 1024;
constexpr int HWSZ   = 4096;   // 64*64
constexpr int BATCH  = 16;
constexpr int NPOS   = BATCH * HWSZ;            // 65536
constexpr int P      = 128;                     // positions per block
constexpr int TK     = 128;                     // codes per k-strip iteration
constexpr int NTILES = KCODES / TK;             // 8
constexpr int THREADS = 512;                    // 8 waves
constexpr size_t QELEMS   = (size_t)BATCH * CDIM * HWSZ;   // 8388608
constexpr size_t IDX_OFF  = QELEMS;                        // float32 elements
constexpr size_t LOSS_OFF = IDX_OFF + (size_t)NPOS;        // 8454144
constexpr size_t PERP_OFF = LOSS_OFF + 1;
// d_ws float-element offsets
constexpr int WS_C2   = 0;      // [0,1024)   float ||c_k||^2 (numpy-bit-exact)
constexpr int WS_HIST = 1024;   // [1024,2048) uint  usage counts
constexpr int WS_LOSS = 2048;   // [2048]     float sum ||z-q||^2
constexpr float INV_TOTAL = 1.0f / (float)QELEMS;
constexpr float INV_NPOS  = 1.0f / (float)NPOS;
}

// Bit-exact replica of numpy pairwise_sum for n=128 contiguous float32 applied
// to elementwise squares: 8 accumulator chains (stride 8), sequential within a
// chain, combined ((r0+r1)+(r2+r3))+((r4+r5)+(r6+r7)). __f*_rn forbids fma
// contraction (numpy multiplies into a temp, then adds — never fused).
__device__ __forceinline__ float np_sumsq_128(const float* v) {
    float r[8];
    #pragma unroll
    for (int j = 0; j < 8; ++j) r[j] = __fmul_rn(v[j], v[j]);
    #pragma unroll
    for (int i = 8; i < 128; i += 8) {
        #pragma unroll
        for (int j = 0; j < 8; ++j)
            r[j] = __fadd_rn(r[j], __fmul_rn(v[i + j], v[i + j]));
    }
    const float s01 = __fadd_rn(r[0], r[1]);
    const float s23 = __fadd_rn(r[2], r[3]);
    const float s45 = __fadd_rn(r[4], r[5]);
    const float s67 = __fadd_rn(r[6], r[7]);
    return __fadd_rn(__fadd_rn(s01, s23), __fadd_rn(s45, s67));
}

// ---- pass 0: codebook norms (numpy-bit-exact) + zero accumulators ----------
__global__ __launch_bounds__(256) void vq_prep(const float* __restrict__ cb,
                                               float* __restrict__ ws) {
    const int k = blockIdx.x * 256 + threadIdx.x;   // 0..1023
    const float* row = cb + (size_t)k * CDIM;
    float rr[CDIM];
    #pragma unroll
    for (int c = 0; c < CDIM; ++c) rr[c] = row[c];
    ws[WS_C2 + k] = np_sumsq_128(rr);
    ((unsigned int*)ws)[WS_HIST + k] = 0u;
    if (k == 0) ws[WS_LOSS] = 0.0f;
}

// helper: 128 FMAs for one channel-quad (4 pos x 8 codes), ascending c within
// the quad (c, c+1, c+2, c+3) — preserves the per-(pos,code) ascending-c chain.
__device__ __forceinline__ void fma_quad(const float4 zv0, const float4 zv1,
                                         const float4 zv2, const float4 zv3,
                                         const float4 cv[8], float a[4][8]) {
    #pragma unroll
    for (int j = 0; j < 8; ++j) {
        a[0][j] = fmaf(zv0.x, cv[j].x, a[0][j]);
        a[0][j] = fmaf(zv1.x, cv[j].y, a[0][j]);
        a[0][j] = fmaf(zv2.x, cv[j].z, a[0][j]);
        a[0][j] = fmaf(zv3.x, cv[j].w, a[0][j]);
        a[1][j] = fmaf(zv0.y, cv[j].x, a[1][j]);
        a[1][j] = fmaf(zv1.y, cv[j].y, a[1][j]);
        a[1][j] = fmaf(zv2.y, cv[j].z, a[1][j]);
        a[1][j] = fmaf(zv3.y, cv[j].w, a[1][j]);
        a[2][j] = fmaf(zv0.z, cv[j].x, a[2][j]);
        a[2][j] = fmaf(zv1.z, cv[j].y, a[2][j]);
        a[2][j] = fmaf(zv2.z, cv[j].z, a[2][j]);
        a[2][j] = fmaf(zv3.z, cv[j].w, a[2][j]);
        a[3][j] = fmaf(zv0.w, cv[j].x, a[3][j]);
        a[3][j] = fmaf(zv1.w, cv[j].y, a[3][j]);
        a[3][j] = fmaf(zv2.w, cv[j].z, a[3][j]);
        a[3][j] = fmaf(zv3.w, cv[j].w, a[3][j]);
    }
}

// ---- pass 1: register-blocked argmin, codes streamed from L2 ---------------
// Round 11. R10 diagnosis: codes-from-L2 concept is sound (correctness ok,
// LDS wall gone) but compiler settled on VGPR=64 -> no prefetch room -> code
// loads issued just-in-time -> ~200cy exposed L2 latency per chunk ->
// VALUBusy 49%, 315us. Fix: EXPLICIT 1-chunk-ahead software pipeline with two
// named 8xfloat4 buffers (cvA/cvB, static indexing, transient within the
// c4-loop — NOT the R4 live-across-barrier spill pattern), and
// launch_bounds(512,2) so the allocator has register room (~130 est). Loads
// for chunk c+1 issue before chunk c's 128 FMAs (~512cy) — covers L2 latency.
// z stays in LDS (proven conflict-free, wall ~82us). Main loop: no barriers.
// WRITE_SIZE is the spill tripwire (34MB good / 250MB = scratch).
// Bit-exactness: per (pos,code) ONE ascending-c fma chain (c,c+1,c+2,c+3 in
// quad, quads ascend); z2 numpy pairwise 8-chain; d = fl(fl(z2-2zc)+c2);
// strict-< ascending-k; cross-subset lexicographic (d,k) min (shfl pair +
// 8-way LDS) == np.argmin first-index tie-break over disjoint subsets.
__global__ __launch_bounds__(512, 2) void vq_main(const float* __restrict__ z,
                                                  const float* __restrict__ cb,
                                                  float* __restrict__ ws,
                                                  float* __restrict__ out) {
    __shared__ __align__(16) float zt[CDIM][P];     // 64 KB  zt[c][p]
    __shared__ float z2s[P];                        // 512 B
    __shared__ float bdls[8][P];                    // 4 KB  per-cg-pair best_d
    __shared__ int   bkls[8][P];                    // 4 KB  per-cg-pair best_k
    __shared__ int   wkls[P];                       // 512 B winning code
    __shared__ float red[THREADS];                  // 2 KB   (total ~75 KB)

    const int tid   = threadIdx.x;
    const int nbase = blockIdx.x * P;
    const int b     = nbase >> 12;          // 4096 positions per batch image
    const int hw0   = nbase & (HWSZ - 1);   // 128-aligned
    const float* zb = z + (size_t)b * CDIM * HWSZ + hw0;

    // ---- stage z strip: zt[c][p] = z[b][c][hw0+p] (coalesced) --------------
    #pragma unroll
    for (int i = 0; i < (CDIM * P / 4) / THREADS; ++i) {   // 8 iters
        const int linear = i * THREADS + tid;              // 0..4095
        const int c  = linear >> 5;                        // 32 float4 per row
        const int p4 = (linear & 31) * 4;
        *(float4*)&zt[c][p4] = *(const float4*)(zb + (size_t)c * HWSZ + p4);
    }
    __syncthreads();

    // ---- z2 per position: numpy pairwise 8-chain, streamed from LDS --------
    if (tid < P) {
        const int p = tid;
        float r[8];
        #pragma unroll
        for (int j = 0; j < 8; ++j) {
            const float x = zt[j][p];
            r[j] = __fmul_rn(x, x);
        }
        #pragma unroll
        for (int i = 8; i < CDIM; i += 8) {
            #pragma unroll
            for (int j = 0; j < 8; ++j) {
                const float x = zt[i + j][p];
                r[j] = __fadd_rn(r[j], __fmul_rn(x, x));
            }
        }
        const float s01 = __fadd_rn(r[0], r[1]);
        const float s23 = __fadd_rn(r[2], r[3]);
        const float s45 = __fadd_rn(r[4], r[5]);
        const float s67 = __fadd_rn(r[6], r[7]);
        z2s[p] = __fadd_rn(__fadd_rn(s01, s23), __fadd_rn(s45, s67));
    }
    __syncthreads();

    const int pg = tid & 31;      // position group: p0..p0+3  (32 groups)
    const int cg = tid >> 5;      // code group 0..15: codes k0..k0+7 per strip
    const int p0 = pg * 4;
    const int k0 = cg * 8;
    const float* c2g = ws + WS_C2;
    const float4* cb4 = (const float4*)cb;   // 32 float4 per codebook row

    float z2r[4];
    #pragma unroll
    for (int i = 0; i < 4; ++i) z2r[i] = z2s[p0 + i];

    float bestd[4] = {INFINITY, INFINITY, INFINITY, INFINITY};
    int   bestk[4] = {0, 0, 0, 0};

    // ---- main loop: NO barriers; codes streamed from L2, pipelined ---------
    for (int t = 0; t < NTILES; ++t) {
        const int kb = t * TK + k0;
        const float4* crow = cb4 + (size_t)kb * 32;

        float a[4][8];
        #pragma unroll
        for (int i = 0; i < 4; ++i)
            #pragma unroll
            for (int j = 0; j < 8; ++j) a[i][j] = 0.0f;

        float4 cvA[8], cvB[8];
        #pragma unroll
        for (int j = 0; j < 8; ++j) cvA[j] = crow[(size_t)j * 32 + 0];

        for (int c4 = 0; c4 < CDIM / 4; c4 += 2) {
            // prefetch chunk c4+1 into B (always exists: c4 <= 30)
            #pragma unroll
            for (int j = 0; j < 8; ++j) cvB[j] = crow[(size_t)j * 32 + (c4 + 1)];
            {   // compute chunk c4 with A
                const int c = c4 * 4;
                const float4 zv0 = *(const float4*)&zt[c + 0][p0];
                const float4 zv1 = *(const float4*)&zt[c + 1][p0];
                const float4 zv2 = *(const float4*)&zt[c + 2][p0];
                const float4 zv3 = *(const float4*)&zt[c + 3][p0];
                fma_quad(zv0, zv1, zv2, zv3, cvA, a);
            }
            // prefetch chunk c4+2 into A
            if (c4 + 2 < CDIM / 4) {
                #pragma unroll
                for (int j = 0; j < 8; ++j)
                    cvA[j] = crow[(size_t)j * 32 + (c4 + 2)];
            }
            {   // compute chunk c4+1 with B
                const int c = (c4 + 1) * 4;
                const float4 zv0 = *(const float4*)&zt[c + 0][p0];
                const float4 zv1 = *(const float4*)&zt[c + 1][p0];
                const float4 zv2 = *(const float4*)&zt[c + 2][p0];
                const float4 zv3 = *(const float4*)&zt[c + 3][p0];
                fma_quad(zv0, zv1, zv2, zv3, cvB, a);
            }
        }

        // d = fl(fl(z2 - 2*zc) + c2); strict < with ascending k (t, then j)
        #pragma unroll
        for (int j = 0; j < 8; ++j) {
            const float c2 = c2g[kb + j];
            #pragma unroll
            for (int i = 0; i < 4; ++i) {
                const float d = __fadd_rn(fmaf(-2.0f, a[i][j], z2r[i]), c2);
                if (d < bestd[i]) { bestd[i] = d; bestk[i] = kb + j; }
            }
        }
    }

    // ---- combine cg pairs (cg, cg^1) in-wave via shfl_xor(32) --------------
    #pragma unroll
    for (int i = 0; i < 4; ++i) {
        const float od = __shfl_xor(bestd[i], 32);
        const int   ok = __shfl_xor(bestk[i], 32);
        if (od < bestd[i] || (od == bestd[i] && ok < bestk[i])) {
            bestd[i] = od; bestk[i] = ok;
        }
    }
    if ((tid & 32) == 0) {
        #pragma unroll
        for (int i = 0; i < 4; ++i) {
            bdls[cg >> 1][p0 + i] = bestd[i];
            bkls[cg >> 1][p0 + i] = bestk[i];
        }
    }
    __syncthreads();

    // ---- combine 8 disjoint code-subsets per position; lexicographic (d,k)
    unsigned int* ghist = (unsigned int*)ws + WS_HIST;
    if (tid < P) {
        const int p = tid;
        float bd = bdls[0][p];
        int   bk = bkls[0][p];
        #pragma unroll
        for (int g = 1; g < 8; ++g) {
            const float d = bdls[g][p];
            const int   k = bkls[g][p];
            if (d < bd || (d == bd && k < bk)) { bd = d; bk = k; }
        }
        wkls[p] = bk;
        out[IDX_OFF + (size_t)(nbase + p)] = (float)bk;
        atomicAdd(&ghist[bk], 1u);       // 128/block, 1024 bins: low contention
        red[tid] = bd;     // best_d == fl(||z-q||^2), loss has 2% slack
    } else {
        red[tid] = 0.0f;
    }
    __syncthreads();
    for (int s = THREADS / 2; s > 0; s >>= 1) {
        if (tid < s) red[tid] += red[tid + s];
        __syncthreads();
    }
    if (tid == 0) atomicAdd(&ws[WS_LOSS], red[0]);

    // ---- quantized output: out[b][c][hw0+p] = cb[wk[p]][c] -----------------
    // stores coalesced (512B per c-row); cb gather L1/L2-hot.
    float* ob = out + (size_t)b * CDIM * HWSZ + hw0;
    #pragma unroll
    for (int i = 0; i < (CDIM * P) / THREADS; ++i) {   // 32 iters
        const int linear = i * THREADS + tid;          // 0..16383
        const int c = linear >> 7;
        const int p = linear & 127;
        ob[(size_t)c * HWSZ + p] = cb[(size_t)wkls[p] * CDIM + c];
    }
}

// ---- pass 2: scalars --------------------------------------------------------
__global__ __launch_bounds__(1024) void vq_final(const float* __restrict__ ws,
                                                 float* __restrict__ out) {
    __shared__ float red[1024];
    const int t = threadIdx.x;
    const unsigned int* hist = (const unsigned int*)ws + WS_HIST;
    const float p = (float)hist[t] * INV_NPOS;
    red[t] = p * logf(p + 1e-10f);
    __syncthreads();
    for (int s = 512; s > 0; s >>= 1) {
        if (t < s) red[t] += red[t + s];
        __syncthreads();
    }
    if (t == 0) {
        out[LOSS_OFF] = 1.25f * (ws[WS_LOSS] * INV_TOTAL);   // cb + 0.25*commit
        out[PERP_OFF] = expf(-red[0]);
    }
}

extern "C" void kernel_launch(void* const* d_in, const int* in_sizes, int n_in,
                              void* d_out, int out_size, void* d_ws, size_t ws_size,
                              hipStream_t stream) {
    const float* z  = (const float*)d_in[0];
    const float* cb = (const float*)d_in[1];
    float* out = (float*)d_out;
    float* ws  = (float*)d_ws;

    vq_prep <<<KCODES / 256, 256, 0, stream>>>(cb, ws);
    vq_main <<<NPOS / P,     THREADS, 0, stream>>>(z, cb, ws, out);
    vq_final<<<1,           1024, 0, stream>>>(ws, out);
}

// Round 12
// 302.593 us; speedup vs baseline: 1.2097x; 1.2097x over previous
//
#include <hip/hip_runtime.h>
#include <math.h>

namespace {
constexpr int CDIM   = 128;
constexpr int KCODES = 1024;
constexpr int HWSZ   = 4096;   // 64*64
constexpr int BATCH  = 16;
constexpr int NPOS   = BATCH * HWSZ;            // 65536
constexpr int P      = 256;                     // positions per block
constexpr int NWAVES = 8;                       // 512 threads
constexpr int KPW    = KCODES / NWAVES;         // 128 codes per wave
constexpr int THREADS = 512;
constexpr size_t QELEMS   = (size_t)BATCH * CDIM * HWSZ;   // 8388608
constexpr size_t IDX_OFF  = QELEMS;                        // float32 elements
constexpr size_t LOSS_OFF = IDX_OFF + (size_t)NPOS;        // 8454144
constexpr size_t PERP_OFF = LOSS_OFF + 1;
// d_ws float-element offsets
constexpr int WS_C2   = 0;      // [0,1024)   float ||c_k||^2 (numpy-bit-exact)
constexpr int WS_HIST = 1024;   // [1024,2048) uint  usage counts
constexpr int WS_LOSS = 2048;   // [2048]     float sum ||z-q||^2
constexpr float INV_TOTAL = 1.0f / (float)QELEMS;
constexpr float INV_NPOS  = 1.0f / (float)NPOS;
}

// Bit-exact replica of numpy pairwise_sum for n=128 contiguous float32 applied
// to elementwise squares: 8 accumulator chains (stride 8), sequential within a
// chain, combined ((r0+r1)+(r2+r3))+((r4+r5)+(r6+r7)). __f*_rn forbids fma
// contraction (numpy multiplies into a temp, then adds — never fused).
__device__ __forceinline__ float np_sumsq_128(const float* v) {
    float r[8];
    #pragma unroll
    for (int j = 0; j < 8; ++j) r[j] = __fmul_rn(v[j], v[j]);
    #pragma unroll
    for (int i = 8; i < 128; i += 8) {
        #pragma unroll
        for (int j = 0; j < 8; ++j)
            r[j] = __fadd_rn(r[j], __fmul_rn(v[i + j], v[i + j]));
    }
    const float s01 = __fadd_rn(r[0], r[1]);
    const float s23 = __fadd_rn(r[2], r[3]);
    const float s45 = __fadd_rn(r[4], r[5]);
    const float s67 = __fadd_rn(r[6], r[7]);
    return __fadd_rn(__fadd_rn(s01, s23), __fadd_rn(s45, s67));
}

// ---- pass 0: codebook norms (numpy-bit-exact) + zero accumulators ----------
__global__ __launch_bounds__(256) void vq_prep(const float* __restrict__ cb,
                                               float* __restrict__ ws) {
    const int k = blockIdx.x * 256 + threadIdx.x;   // 0..1023
    const float* row = cb + (size_t)k * CDIM;
    float rr[CDIM];
    #pragma unroll
    for (int c = 0; c < CDIM; ++c) rr[c] = row[c];
    ws[WS_C2 + k] = np_sumsq_128(rr);
    ((unsigned int*)ws)[WS_HIST + k] = 0u;
    if (k == 0) ws[WS_LOSS] = 0.0f;
}

// ---- pass 1: codes via SGPR (s_load), z via LDS -----------------------------
// Round 12. R10/R11 lesson (4th confirmation): VMEM->VGPR prefetch pipelines
// in HIP source are collapsed by the allocator (VGPR 64/88, loads sunk to
// just-in-time, ~200cy exposed). Fix: exploit that code values are WAVE-
// UNIFORM when each wave owns a contiguous code strip. readfirstlane(wid)
// makes all code addresses provably scalar -> compiler emits s_load into
// SGPRs: different register file (no VGPR fight), different pipe (scalar/
// constant cache; VMEM and LDS untouched), and v_fma_f32 v,v,s,v takes one
// SGPR operand directly. Structure: 8 waves x [all 256 positions, 128-code
// strip each]. Per chunk/wave: 4 ds_read_b128 (z, lane-contiguous 1024B =
// max-rate conflict-free) + 8 s_load_dwordx4 + 128 FMA. LDS/CU 384cy < VALU
// 512cy -> VALU-bound; no barriers in main loop; 2 waves/SIMD stagger covers
// chunk latency. Accs stay 32 (proven compile size).
// Bit-exactness: per (pos,code) ONE ascending-c fma chain (c,c+1,c+2,c+3 in
// quad, quads ascend); z2 numpy pairwise 8-chain; d = fl(fl(z2-2zc)+c2);
// strict-< with ascending k inside each wave's contiguous ascending strip;
// cross-wave lexicographic (d,k) min == np.argmin first-index tie-break.
__global__ __launch_bounds__(512, 1) void vq_main(const float* __restrict__ z,
                                                  const float* __restrict__ cb,
                                                  float* __restrict__ ws,
                                                  float* __restrict__ out) {
    __shared__ __align__(16) float zt[CDIM][P];     // 128 KB  zt[c][p]
    __shared__ float z2s[P];                        // 1 KB
    __shared__ float bdls[NWAVES][P];               // 8 KB  per-wave best_d
    __shared__ int   bkls[NWAVES][P];               // 8 KB  per-wave best_k
    __shared__ int   wkls[P];                       // 1 KB  winning code
    __shared__ float red[THREADS];                  // 2 KB   (total 148 KB)

    const int tid   = threadIdx.x;
    const int nbase = blockIdx.x * P;
    const int b     = nbase >> 12;          // 4096 positions per batch image
    const int hw0   = nbase & (HWSZ - 1);   // 256-aligned
    const float* zb = z + (size_t)b * CDIM * HWSZ + hw0;

    // ---- stage z strip: zt[c][p] = z[b][c][hw0+p] (coalesced) --------------
    #pragma unroll
    for (int i = 0; i < (CDIM * P / 4) / THREADS; ++i) {   // 16 iters
        const int linear = i * THREADS + tid;              // 0..8191
        const int c  = linear >> 6;                        // 64 float4 per row
        const int p4 = (linear & 63) * 4;
        *(float4*)&zt[c][p4] = *(const float4*)(zb + (size_t)c * HWSZ + p4);
    }
    __syncthreads();

    // ---- z2 per position: numpy pairwise 8-chain, streamed from LDS --------
    if (tid < P) {
        const int p = tid;
        float r[8];
        #pragma unroll
        for (int j = 0; j < 8; ++j) {
            const float x = zt[j][p];
            r[j] = __fmul_rn(x, x);
        }
        #pragma unroll
        for (int i = 8; i < CDIM; i += 8) {
            #pragma unroll
            for (int j = 0; j < 8; ++j) {
                const float x = zt[i + j][p];
                r[j] = __fadd_rn(r[j], __fmul_rn(x, x));
            }
        }
        const float s01 = __fadd_rn(r[0], r[1]);
        const float s23 = __fadd_rn(r[2], r[3]);
        const float s45 = __fadd_rn(r[4], r[5]);
        const float s67 = __fadd_rn(r[6], r[7]);
        z2s[p] = __fadd_rn(__fadd_rn(s01, s23), __fadd_rn(s45, s67));
    }
    __syncthreads();

    const int lane = tid & 63;
    const int p0   = lane * 4;              // each lane owns 4 positions
    // readfirstlane makes the wave id PROVABLY scalar -> all code addresses
    // derived from it are scalar -> compiler emits s_load (SGPR destination).
    const int wid  = __builtin_amdgcn_readfirstlane(tid >> 6);
    const int kw   = wid * KPW;             // wave's contiguous code strip
    const float* c2g = ws + WS_C2;

    float z2r[4];
    #pragma unroll
    for (int i = 0; i < 4; ++i) z2r[i] = z2s[p0 + i];

    float bestd[4] = {INFINITY, INFINITY, INFINITY, INFINITY};
    int   bestk[4] = {0, 0, 0, 0};

    // ---- main loop: NO barriers; codes via scalar loads --------------------
    for (int oct = 0; oct < KPW / 8; ++oct) {      // 16 octets of 8 codes
        const int kb = kw + oct * 8;
        const float* coct = cb + (size_t)kb * CDIM;   // scalar base

        float a[4][8];
        #pragma unroll
        for (int i = 0; i < 4; ++i)
            #pragma unroll
            for (int j = 0; j < 8; ++j) a[i][j] = 0.0f;

        #pragma unroll 2
        for (int c4 = 0; c4 < CDIM / 4; ++c4) {
            const int c = c4 * 4;
            const float4 zv0 = *(const float4*)&zt[c + 0][p0];
            const float4 zv1 = *(const float4*)&zt[c + 1][p0];
            const float4 zv2 = *(const float4*)&zt[c + 2][p0];
            const float4 zv3 = *(const float4*)&zt[c + 3][p0];
            float4 cv[8];   // scalar (SGPR) values, uniform across the wave
            #pragma unroll
            for (int j = 0; j < 8; ++j)
                cv[j] = *(const float4*)(coct + (size_t)j * CDIM + c);
            #pragma unroll
            for (int j = 0; j < 8; ++j) {
                a[0][j] = fmaf(zv0.x, cv[j].x, a[0][j]);
                a[0][j] = fmaf(zv1.x, cv[j].y, a[0][j]);
                a[0][j] = fmaf(zv2.x, cv[j].z, a[0][j]);
                a[0][j] = fmaf(zv3.x, cv[j].w, a[0][j]);
                a[1][j] = fmaf(zv0.y, cv[j].x, a[1][j]);
                a[1][j] = fmaf(zv1.y, cv[j].y, a[1][j]);
                a[1][j] = fmaf(zv2.y, cv[j].z, a[1][j]);
                a[1][j] = fmaf(zv3.y, cv[j].w, a[1][j]);
                a[2][j] = fmaf(zv0.z, cv[j].x, a[2][j]);
                a[2][j] = fmaf(zv1.z, cv[j].y, a[2][j]);
                a[2][j] = fmaf(zv2.z, cv[j].z, a[2][j]);
                a[2][j] = fmaf(zv3.z, cv[j].w, a[2][j]);
                a[3][j] = fmaf(zv0.w, cv[j].x, a[3][j]);
                a[3][j] = fmaf(zv1.w, cv[j].y, a[3][j]);
                a[3][j] = fmaf(zv2.w, cv[j].z, a[3][j]);
                a[3][j] = fmaf(zv3.w, cv[j].w, a[3][j]);
            }
        }

        // d = fl(fl(z2 - 2*zc) + c2); strict < with ascending k
        #pragma unroll
        for (int j = 0; j < 8; ++j) {
            const float c2 = c2g[kb + j];
            #pragma unroll
            for (int i = 0; i < 4; ++i) {
                const float d = __fadd_rn(fmaf(-2.0f, a[i][j], z2r[i]), c2);
                if (d < bestd[i]) { bestd[i] = d; bestk[i] = kb + j; }
            }
        }
    }

    // ---- per-wave results: wave wid covers all 256 positions ---------------
    #pragma unroll
    for (int i = 0; i < 4; ++i) {
        bdls[wid][p0 + i] = bestd[i];
        bkls[wid][p0 + i] = bestk[i];
    }
    __syncthreads();

    // ---- combine 8 disjoint code-strips per position; lexicographic (d,k)
    unsigned int* ghist = (unsigned int*)ws + WS_HIST;
    if (tid < P) {
        const int p = tid;
        float bd = bdls[0][p];
        int   bk = bkls[0][p];
        #pragma unroll
        for (int g = 1; g < NWAVES; ++g) {
            const float d = bdls[g][p];
            const int   k = bkls[g][p];
            if (d < bd || (d == bd && k < bk)) { bd = d; bk = k; }
        }
        wkls[p] = bk;
        out[IDX_OFF + (size_t)(nbase + p)] = (float)bk;
        atomicAdd(&ghist[bk], 1u);       // 256/block, 1024 bins: low contention
        red[tid] = bd;     // best_d == fl(||z-q||^2), loss has 2% slack
    } else {
        red[tid] = 0.0f;
    }
    __syncthreads();
    for (int s = THREADS / 2; s > 0; s >>= 1) {
        if (tid < s) red[tid] += red[tid + s];
        __syncthreads();
    }
    if (tid == 0) atomicAdd(&ws[WS_LOSS], red[0]);

    // ---- quantized output: out[b][c][hw0+p] = cb[wk[p]][c] -----------------
    // stores coalesced (1024B per c-row); cb gather L1/L2-hot.
    float* ob = out + (size_t)b * CDIM * HWSZ + hw0;
    #pragma unroll
    for (int i = 0; i < (CDIM * P) / THREADS; ++i) {   // 64 iters
        const int linear = i * THREADS + tid;          // 0..32767
        const int c = linear >> 8;
        const int p = linear & 255;
        ob[(size_t)c * HWSZ + p] = cb[(size_t)wkls[p] * CDIM + c];
    }
}

// ---- pass 2: scalars --------------------------------------------------------
__global__ __launch_bounds__(1024) void vq_final(const float* __restrict__ ws,
                                                 float* __restrict__ out) {
    __shared__ float red[1024];
    const int t = threadIdx.x;
    const unsigned int* hist = (const unsigned int*)ws + WS_HIST;
    const float p = (float)hist[t] * INV_NPOS;
    red[t] = p * logf(p + 1e-10f);
    __syncthreads();
    for (int s = 512; s > 0; s >>= 1) {
        if (t < s) red[t] += red[t + s];
        __syncthreads();
    }
    if (t == 0) {
        out[LOSS_OFF] = 1.25f * (ws[WS_LOSS] * INV_TOTAL);   // cb + 0.25*commit
        out[PERP_OFF] = expf(-red[0]);
    }
}

extern "C" void kernel_launch(void* const* d_in, const int* in_sizes, int n_in,
                              void* d_out, int out_size, void* d_ws, size_t ws_size,
                              hipStream_t stream) {
    const float* z  = (const float*)d_in[0];
    const float* cb = (const float*)d_in[1];
    float* out = (float*)d_out;
    float* ws  = (float*)d_ws;

    vq_prep <<<KCODES / 256, 256, 0, stream>>>(cb, ws);
    vq_main <<<NPOS / P,     THREADS, 0, stream>>>(z, cb, ws, out);
    vq_final<<<1,           1024, 0, stream>>>(ws, out);
}

// Round 13
// 280.711 us; speedup vs baseline: 1.3040x; 1.0779x over previous
//
#include <hip/hip_runtime.h>
#include <math.h>

namespace {
constexpr int CDIM   = 128;
constexpr int KCODES = 1024;
constexpr int HWSZ   = 4096;   // 64*64
constexpr int BATCH  = 16;
constexpr int NPOS   = BATCH * HWSZ;            // 65536
constexpr int P      = 128;                     // positions per block
constexpr int NWAVES = 8;                       // 512 threads
constexpr int KPW    = KCODES / NWAVES;         // 128 codes per wave
constexpr int THREADS = 512;
constexpr size_t QELEMS   = (size_t)BATCH * CDIM * HWSZ;   // 8388608
constexpr size_t IDX_OFF  = QELEMS;                        // float32 elements
constexpr size_t LOSS_OFF = IDX_OFF + (size_t)NPOS;        // 8454144
constexpr size_t PERP_OFF = LOSS_OFF + 1;
// d_ws float-element offsets
constexpr int WS_C2   = 0;      // [0,1024)   float ||c_k||^2 (numpy-bit-exact)
constexpr int WS_HIST = 1024;   // [1024,2048) uint  usage counts
constexpr int WS_LOSS = 2048;   // [2048]     float sum ||z-q||^2
constexpr float INV_TOTAL = 1.0f / (float)QELEMS;
constexpr float INV_NPOS  = 1.0f / (float)NPOS;
}

// Bit-exact replica of numpy pairwise_sum for n=128 contiguous float32 applied
// to elementwise squares: 8 accumulator chains (stride 8), sequential within a
// chain, combined ((r0+r1)+(r2+r3))+((r4+r5)+(r6+r7)). __f*_rn forbids fma
// contraction (numpy multiplies into a temp, then adds — never fused).
__device__ __forceinline__ float np_sumsq_128(const float* v) {
    float r[8];
    #pragma unroll
    for (int j = 0; j < 8; ++j) r[j] = __fmul_rn(v[j], v[j]);
    #pragma unroll
    for (int i = 8; i < 128; i += 8) {
        #pragma unroll
        for (int j = 0; j < 8; ++j)
            r[j] = __fadd_rn(r[j], __fmul_rn(v[i + j], v[i + j]));
    }
    const float s01 = __fadd_rn(r[0], r[1]);
    const float s23 = __fadd_rn(r[2], r[3]);
    const float s45 = __fadd_rn(r[4], r[5]);
    const float s67 = __fadd_rn(r[6], r[7]);
    return __fadd_rn(__fadd_rn(s01, s23), __fadd_rn(s45, s67));
}

// ---- pass 0: codebook norms (numpy-bit-exact) + zero accumulators ----------
__global__ __launch_bounds__(256) void vq_prep(const float* __restrict__ cb,
                                               float* __restrict__ ws) {
    const int k = blockIdx.x * 256 + threadIdx.x;   // 0..1023
    const float* row = cb + (size_t)k * CDIM;
    float rr[CDIM];
    #pragma unroll
    for (int c = 0; c < CDIM; ++c) rr[c] = row[c];
    ws[WS_C2 + k] = np_sumsq_128(rr);
    ((unsigned int*)ws)[WS_HIST + k] = 0u;
    if (k == 0) ws[WS_LOSS] = 0.0f;
}

// ---- pass 1: codes via SGPR (s_load), z via LDS, 4 waves/SIMD --------------
// Round 13. R12 (SGPR codes, 2 waves/SIMD, 148KB LDS): 252us best, VALUBusy
// 52.7%. Per-chunk lgkmcnt stall (~300cy mixed DS+SMEM drain) vs 512cy of
// combined FMA from 2 waves -> ~55% busy ceiling. The only lever that ever
// moved VALUBusy was wave count (R3->R9 +12pts); R10's extra waves were
// confounded by the VGPR-64 load-sinking pathology, which the SGPR path
// removes. So: SAME R12 structure, HALF the position strip. P=128, each lane
// owns 2 positions (16 accs), wave owns a 128-code strip via s_load. LDS
// 148->75KB -> 2 blocks/CU = 16 waves/CU = 4 waves/SIMD: 4x128cy FMA per
// chunk-slot covers the ~300cy stall. DS: 4 ds_read_b64/chunk (BW-bound,
// ~4cy) = well under the LDS wall. launch_bounds(512,4) caps VGPR 128 —
// harmless (~70 live, codes in SGPRs; R10 trap doesn't apply). Grid 512 =
// one co-resident generation. WRITE_SIZE = spill tripwire (34MB good).
// Bit-exactness: per (pos,code) ONE ascending-c fma chain (c,c+1,c+2,c+3 in
// quad, quads ascend); z2 numpy pairwise 8-chain; d = fl(fl(z2-2zc)+c2);
// strict-< with ascending k inside each wave's contiguous ascending strip;
// cross-wave lexicographic (d,k) min == np.argmin first-index tie-break.
__global__ __launch_bounds__(512, 4) void vq_main(const float* __restrict__ z,
                                                  const float* __restrict__ cb,
                                                  float* __restrict__ ws,
                                                  float* __restrict__ out) {
    __shared__ __align__(16) float zt[CDIM][P];     // 64 KB  zt[c][p]
    __shared__ float z2s[P];                        // 512 B
    __shared__ float bdls[NWAVES][P];               // 4 KB  per-wave best_d
    __shared__ int   bkls[NWAVES][P];               // 4 KB  per-wave best_k
    __shared__ int   wkls[P];                       // 512 B winning code
    __shared__ float red[THREADS];                  // 2 KB   (total 75 KB)

    const int tid   = threadIdx.x;
    const int nbase = blockIdx.x * P;
    const int b     = nbase >> 12;          // 4096 positions per batch image
    const int hw0   = nbase & (HWSZ - 1);   // 128-aligned
    const float* zb = z + (size_t)b * CDIM * HWSZ + hw0;

    // ---- stage z strip: zt[c][p] = z[b][c][hw0+p] (coalesced) --------------
    #pragma unroll
    for (int i = 0; i < (CDIM * P / 4) / THREADS; ++i) {   // 8 iters
        const int linear = i * THREADS + tid;              // 0..4095
        const int c  = linear >> 5;                        // 32 float4 per row
        const int p4 = (linear & 31) * 4;
        *(float4*)&zt[c][p4] = *(const float4*)(zb + (size_t)c * HWSZ + p4);
    }
    __syncthreads();

    // ---- z2 per position: numpy pairwise 8-chain, streamed from LDS --------
    if (tid < P) {
        const int p = tid;
        float r[8];
        #pragma unroll
        for (int j = 0; j < 8; ++j) {
            const float x = zt[j][p];
            r[j] = __fmul_rn(x, x);
        }
        #pragma unroll
        for (int i = 8; i < CDIM; i += 8) {
            #pragma unroll
            for (int j = 0; j < 8; ++j) {
                const float x = zt[i + j][p];
                r[j] = __fadd_rn(r[j], __fmul_rn(x, x));
            }
        }
        const float s01 = __fadd_rn(r[0], r[1]);
        const float s23 = __fadd_rn(r[2], r[3]);
        const float s45 = __fadd_rn(r[4], r[5]);
        const float s67 = __fadd_rn(r[6], r[7]);
        z2s[p] = __fadd_rn(__fadd_rn(s01, s23), __fadd_rn(s45, s67));
    }
    __syncthreads();

    const int lane = tid & 63;
    const int p0   = lane * 2;              // each lane owns 2 positions
    // readfirstlane makes the wave id PROVABLY scalar -> all code addresses
    // derived from it are scalar -> compiler emits s_load (SGPR destination).
    const int wid  = __builtin_amdgcn_readfirstlane(tid >> 6);
    const int kw   = wid * KPW;             // wave's contiguous code strip
    const float* c2g = ws + WS_C2;

    float z2r[2];
    z2r[0] = z2s[p0 + 0];
    z2r[1] = z2s[p0 + 1];

    float bestd[2] = {INFINITY, INFINITY};
    int   bestk[2] = {0, 0};

    // ---- main loop: NO barriers; codes via scalar loads --------------------
    for (int oct = 0; oct < KPW / 8; ++oct) {      // 16 octets of 8 codes
        const int kb = kw + oct * 8;
        const float* coct = cb + (size_t)kb * CDIM;   // scalar base

        float a[2][8];
        #pragma unroll
        for (int j = 0; j < 8; ++j) { a[0][j] = 0.0f; a[1][j] = 0.0f; }

        #pragma unroll 2
        for (int c4 = 0; c4 < CDIM / 4; ++c4) {
            const int c = c4 * 4;
            const float2 zv0 = *(const float2*)&zt[c + 0][p0];
            const float2 zv1 = *(const float2*)&zt[c + 1][p0];
            const float2 zv2 = *(const float2*)&zt[c + 2][p0];
            const float2 zv3 = *(const float2*)&zt[c + 3][p0];
            float4 cv[8];   // scalar (SGPR) values, uniform across the wave
            #pragma unroll
            for (int j = 0; j < 8; ++j)
                cv[j] = *(const float4*)(coct + (size_t)j * CDIM + c);
            #pragma unroll
            for (int j = 0; j < 8; ++j) {
                a[0][j] = fmaf(zv0.x, cv[j].x, a[0][j]);
                a[0][j] = fmaf(zv1.x, cv[j].y, a[0][j]);
                a[0][j] = fmaf(zv2.x, cv[j].z, a[0][j]);
                a[0][j] = fmaf(zv3.x, cv[j].w, a[0][j]);
                a[1][j] = fmaf(zv0.y, cv[j].x, a[1][j]);
                a[1][j] = fmaf(zv1.y, cv[j].y, a[1][j]);
                a[1][j] = fmaf(zv2.y, cv[j].z, a[1][j]);
                a[1][j] = fmaf(zv3.y, cv[j].w, a[1][j]);
            }
        }

        // d = fl(fl(z2 - 2*zc) + c2); strict < with ascending k
        #pragma unroll
        for (int j = 0; j < 8; ++j) {
            const float c2 = c2g[kb + j];
            const float d0 = __fadd_rn(fmaf(-2.0f, a[0][j], z2r[0]), c2);
            const float d1 = __fadd_rn(fmaf(-2.0f, a[1][j], z2r[1]), c2);
            if (d0 < bestd[0]) { bestd[0] = d0; bestk[0] = kb + j; }
            if (d1 < bestd[1]) { bestd[1] = d1; bestk[1] = kb + j; }
        }
    }

    // ---- per-wave results: wave wid covers all 128 positions ---------------
    bdls[wid][p0 + 0] = bestd[0];
    bdls[wid][p0 + 1] = bestd[1];
    bkls[wid][p0 + 0] = bestk[0];
    bkls[wid][p0 + 1] = bestk[1];
    __syncthreads();

    // ---- combine 8 disjoint code-strips per position; lexicographic (d,k)
    unsigned int* ghist = (unsigned int*)ws + WS_HIST;
    if (tid < P) {
        const int p = tid;
        float bd = bdls[0][p];
        int   bk = bkls[0][p];
        #pragma unroll
        for (int g = 1; g < NWAVES; ++g) {
            const float d = bdls[g][p];
            const int   k = bkls[g][p];
            if (d < bd || (d == bd && k < bk)) { bd = d; bk = k; }
        }
        wkls[p] = bk;
        out[IDX_OFF + (size_t)(nbase + p)] = (float)bk;
        atomicAdd(&ghist[bk], 1u);       // 128/block, 1024 bins: low contention
        red[tid] = bd;     // best_d == fl(||z-q||^2), loss has 2% slack
    } else {
        red[tid] = 0.0f;
    }
    __syncthreads();
    for (int s = THREADS / 2; s > 0; s >>= 1) {
        if (tid < s) red[tid] += red[tid + s];
        __syncthreads();
    }
    if (tid == 0) atomicAdd(&ws[WS_LOSS], red[0]);

    // ---- quantized output: out[b][c][hw0+p] = cb[wk[p]][c] -----------------
    // stores coalesced (512B per c-row); cb gather L1/L2-hot.
    float* ob = out + (size_t)b * CDIM * HWSZ + hw0;
    #pragma unroll
    for (int i = 0; i < (CDIM * P) / THREADS; ++i) {   // 32 iters
        const int linear = i * THREADS + tid;          // 0..16383
        const int c = linear >> 7;
        const int p = linear & 127;
        ob[(size_t)c * HWSZ + p] = cb[(size_t)wkls[p] * CDIM + c];
    }
}

// ---- pass 2: scalars --------------------------------------------------------
__global__ __launch_bounds__(1024) void vq_final(const float* __restrict__ ws,
                                                 float* __restrict__ out) {
    __shared__ float red[1024];
    const int t = threadIdx.x;
    const unsigned int* hist = (const unsigned int*)ws + WS_HIST;
    const float p = (float)hist[t] * INV_NPOS;
    red[t] = p * logf(p + 1e-10f);
    __syncthreads();
    for (int s = 512; s > 0; s >>= 1) {
        if (t < s) red[t] += red[t + s];
        __syncthreads();
    }
    if (t == 0) {
        out[LOSS_OFF] = 1.25f * (ws[WS_LOSS] * INV_TOTAL);   // cb + 0.25*commit
        out[PERP_OFF] = expf(-red[0]);
    }
}

extern "C" void kernel_launch(void* const* d_in, const int* in_sizes, int n_in,
                              void* d_out, int out_size, void* d_ws, size_t ws_size,
                              hipStream_t stream) {
    const float* z  = (const float*)d_in[0];
    const float* cb = (const float*)d_in[1];
    float* out = (float*)d_out;
    float* ws  = (float*)d_ws;

    vq_prep <<<KCODES / 256, 256, 0, stream>>>(cb, ws);
    vq_main <<<NPOS / P,     THREADS, 0, stream>>>(z, cb, ws, out);
    vq_final<<<1,           1024, 0, stream>>>(ws, out);
}

// Round 14
// 264.245 us; speedup vs baseline: 1.3852x; 1.0623x over previous
//
#include <hip/hip_runtime.h>
#include <math.h>

namespace {
constexpr int CDIM   = 128;
constexpr int KCODES = 1024;
constexpr int HWSZ   = 4096;   // 64*64
constexpr int BATCH  = 16;
constexpr int NPOS   = BATCH * HWSZ;            // 65536
constexpr int P      = 128;                     // positions per block
constexpr int NWAVES = 8;                       // 512 threads
constexpr int KPW    = KCODES / NWAVES;         // 128 codes per wave
constexpr int KT     = 16;                      // codes per inner tile
constexpr int THREADS = 512;
constexpr size_t QELEMS   = (size_t)BATCH * CDIM * HWSZ;   // 8388608
constexpr size_t IDX_OFF  = QELEMS;                        // float32 elements
constexpr size_t LOSS_OFF = IDX_OFF + (size_t)NPOS;        // 8454144
constexpr size_t PERP_OFF = LOSS_OFF + 1;
// d_ws float-element offsets
constexpr int WS_C2   = 0;      // [0,1024)   float ||c_k||^2 (numpy-bit-exact)
constexpr int WS_HIST = 1024;   // [1024,2048) uint  usage counts
constexpr int WS_LOSS = 2048;   // [2048]     float sum ||z-q||^2
constexpr float INV_TOTAL = 1.0f / (float)QELEMS;
constexpr float INV_NPOS  = 1.0f / (float)NPOS;
}

// Bit-exact replica of numpy pairwise_sum for n=128 contiguous float32 applied
// to elementwise squares: 8 accumulator chains (stride 8), sequential within a
// chain, combined ((r0+r1)+(r2+r3))+((r4+r5)+(r6+r7)). __f*_rn forbids fma
// contraction (numpy multiplies into a temp, then adds — never fused).
__device__ __forceinline__ float np_sumsq_128(const float* v) {
    float r[8];
    #pragma unroll
    for (int j = 0; j < 8; ++j) r[j] = __fmul_rn(v[j], v[j]);
    #pragma unroll
    for (int i = 8; i < 128; i += 8) {
        #pragma unroll
        for (int j = 0; j < 8; ++j)
            r[j] = __fadd_rn(r[j], __fmul_rn(v[i + j], v[i + j]));
    }
    const float s01 = __fadd_rn(r[0], r[1]);
    const float s23 = __fadd_rn(r[2], r[3]);
    const float s45 = __fadd_rn(r[4], r[5]);
    const float s67 = __fadd_rn(r[6], r[7]);
    return __fadd_rn(__fadd_rn(s01, s23), __fadd_rn(s45, s67));
}

// ---- pass 0: codebook norms (numpy-bit-exact) + zero accumulators ----------
__global__ __launch_bounds__(256) void vq_prep(const float* __restrict__ cb,
                                               float* __restrict__ ws) {
    const int k = blockIdx.x * 256 + threadIdx.x;   // 0..1023
    const float* row = cb + (size_t)k * CDIM;
    float rr[CDIM];
    #pragma unroll
    for (int c = 0; c < CDIM; ++c) rr[c] = row[c];
    ws[WS_C2 + k] = np_sumsq_128(rr);
    ((unsigned int*)ws)[WS_HIST + k] = 0u;
    if (k == 0) ws[WS_LOSS] = 0.0f;
}

// ---- pass 1: codes via SGPR (s_load), z via LDS, 4 waves/SIMD, wide tile ---
// Round 14. R13 (SGPR codes, 4 waves/SIMD): 230us best, VALUBusy 60.4%. The
// remaining stall is drain FREQUENCY: 512 lgkmcnt(0) drains/wave (mixed
// DS+SMEM forces full drain; SMEM completes unordered), each covering only
// 128cy of FMA — coverage 4x128=512cy vs ~300cy stall is marginal, and sQC
// misses (each wave streams 64KB codebook through the scalar cache) blow it.
// Fix at constant occupancy: widen the code tile 8 -> 16 (cv[16] = 64 SGPRs,
// within ~102 budget; accs 2 pos x 16 codes = 32 = proven size). Per drain:
// 4 ds_read_b64 + 16 s_load_dwordx4 + 256cy FMA; drains halve to 256/wave;
// coverage 4x256=1024cy >> stall. Everything else = R13 (P=128, 75KB LDS,
// 2 blocks/CU, barrier-free main loop). WRITE_SIZE = spill tripwire.
// Bit-exactness: per (pos,code) ONE ascending-c fma chain (c,c+1,c+2,c+3 in
// quad, quads ascend); z2 numpy pairwise 8-chain; d = fl(fl(z2-2zc)+c2);
// strict-< with ascending k (j ascends in tile, tiles ascend, strips
// contiguous); cross-wave lexicographic (d,k) min == np.argmin first-index.
__global__ __launch_bounds__(512, 4) void vq_main(const float* __restrict__ z,
                                                  const float* __restrict__ cb,
                                                  float* __restrict__ ws,
                                                  float* __restrict__ out) {
    __shared__ __align__(16) float zt[CDIM][P];     // 64 KB  zt[c][p]
    __shared__ float z2s[P];                        // 512 B
    __shared__ float bdls[NWAVES][P];               // 4 KB  per-wave best_d
    __shared__ int   bkls[NWAVES][P];               // 4 KB  per-wave best_k
    __shared__ int   wkls[P];                       // 512 B winning code
    __shared__ float red[THREADS];                  // 2 KB   (total 75 KB)

    const int tid   = threadIdx.x;
    const int nbase = blockIdx.x * P;
    const int b     = nbase >> 12;          // 4096 positions per batch image
    const int hw0   = nbase & (HWSZ - 1);   // 128-aligned
    const float* zb = z + (size_t)b * CDIM * HWSZ + hw0;

    // ---- stage z strip: zt[c][p] = z[b][c][hw0+p] (coalesced) --------------
    #pragma unroll
    for (int i = 0; i < (CDIM * P / 4) / THREADS; ++i) {   // 8 iters
        const int linear = i * THREADS + tid;              // 0..4095
        const int c  = linear >> 5;                        // 32 float4 per row
        const int p4 = (linear & 31) * 4;
        *(float4*)&zt[c][p4] = *(const float4*)(zb + (size_t)c * HWSZ + p4);
    }
    __syncthreads();

    // ---- z2 per position: numpy pairwise 8-chain, streamed from LDS --------
    if (tid < P) {
        const int p = tid;
        float r[8];
        #pragma unroll
        for (int j = 0; j < 8; ++j) {
            const float x = zt[j][p];
            r[j] = __fmul_rn(x, x);
        }
        #pragma unroll
        for (int i = 8; i < CDIM; i += 8) {
            #pragma unroll
            for (int j = 0; j < 8; ++j) {
                const float x = zt[i + j][p];
                r[j] = __fadd_rn(r[j], __fmul_rn(x, x));
            }
        }
        const float s01 = __fadd_rn(r[0], r[1]);
        const float s23 = __fadd_rn(r[2], r[3]);
        const float s45 = __fadd_rn(r[4], r[5]);
        const float s67 = __fadd_rn(r[6], r[7]);
        z2s[p] = __fadd_rn(__fadd_rn(s01, s23), __fadd_rn(s45, s67));
    }
    __syncthreads();

    const int lane = tid & 63;
    const int p0   = lane * 2;              // each lane owns 2 positions
    // readfirstlane makes the wave id PROVABLY scalar -> all code addresses
    // derived from it are scalar -> compiler emits s_load (SGPR destination).
    const int wid  = __builtin_amdgcn_readfirstlane(tid >> 6);
    const int kw   = wid * KPW;             // wave's contiguous code strip
    const float* c2g = ws + WS_C2;

    float z2r[2];
    z2r[0] = z2s[p0 + 0];
    z2r[1] = z2s[p0 + 1];

    float bestd[2] = {INFINITY, INFINITY};
    int   bestk[2] = {0, 0};

    // ---- main loop: NO barriers; codes via scalar loads, 16-code tiles -----
    for (int ht = 0; ht < KPW / KT; ++ht) {        // 8 tiles of 16 codes
        const int kb = kw + ht * KT;
        const float* ctile = cb + (size_t)kb * CDIM;  // scalar base

        float a[2][KT];
        #pragma unroll
        for (int j = 0; j < KT; ++j) { a[0][j] = 0.0f; a[1][j] = 0.0f; }

        #pragma unroll 2
        for (int c4 = 0; c4 < CDIM / 4; ++c4) {
            const int c = c4 * 4;
            const float2 zv0 = *(const float2*)&zt[c + 0][p0];
            const float2 zv1 = *(const float2*)&zt[c + 1][p0];
            const float2 zv2 = *(const float2*)&zt[c + 2][p0];
            const float2 zv3 = *(const float2*)&zt[c + 3][p0];
            float4 cv[KT];  // scalar (SGPR) values, uniform across the wave
            #pragma unroll
            for (int j = 0; j < KT; ++j)
                cv[j] = *(const float4*)(ctile + (size_t)j * CDIM + c);
            #pragma unroll
            for (int j = 0; j < KT; ++j) {
                a[0][j] = fmaf(zv0.x, cv[j].x, a[0][j]);
                a[0][j] = fmaf(zv1.x, cv[j].y, a[0][j]);
                a[0][j] = fmaf(zv2.x, cv[j].z, a[0][j]);
                a[0][j] = fmaf(zv3.x, cv[j].w, a[0][j]);
                a[1][j] = fmaf(zv0.y, cv[j].x, a[1][j]);
                a[1][j] = fmaf(zv1.y, cv[j].y, a[1][j]);
                a[1][j] = fmaf(zv2.y, cv[j].z, a[1][j]);
                a[1][j] = fmaf(zv3.y, cv[j].w, a[1][j]);
            }
        }

        // d = fl(fl(z2 - 2*zc) + c2); strict < with ascending k
        #pragma unroll
        for (int j = 0; j < KT; ++j) {
            const float c2 = c2g[kb + j];
            const float d0 = __fadd_rn(fmaf(-2.0f, a[0][j], z2r[0]), c2);
            const float d1 = __fadd_rn(fmaf(-2.0f, a[1][j], z2r[1]), c2);
            if (d0 < bestd[0]) { bestd[0] = d0; bestk[0] = kb + j; }
            if (d1 < bestd[1]) { bestd[1] = d1; bestk[1] = kb + j; }
        }
    }

    // ---- per-wave results: wave wid covers all 128 positions ---------------
    bdls[wid][p0 + 0] = bestd[0];
    bdls[wid][p0 + 1] = bestd[1];
    bkls[wid][p0 + 0] = bestk[0];
    bkls[wid][p0 + 1] = bestk[1];
    __syncthreads();

    // ---- combine 8 disjoint code-strips per position; lexicographic (d,k)
    unsigned int* ghist = (unsigned int*)ws + WS_HIST;
    if (tid < P) {
        const int p = tid;
        float bd = bdls[0][p];
        int   bk = bkls[0][p];
        #pragma unroll
        for (int g = 1; g < NWAVES; ++g) {
            const float d = bdls[g][p];
            const int   k = bkls[g][p];
            if (d < bd || (d == bd && k < bk)) { bd = d; bk = k; }
        }
        wkls[p] = bk;
        out[IDX_OFF + (size_t)(nbase + p)] = (float)bk;
        atomicAdd(&ghist[bk], 1u);       // 128/block, 1024 bins: low contention
        red[tid] = bd;     // best_d == fl(||z-q||^2), loss has 2% slack
    } else {
        red[tid] = 0.0f;
    }
    __syncthreads();
    for (int s = THREADS / 2; s > 0; s >>= 1) {
        if (tid < s) red[tid] += red[tid + s];
        __syncthreads();
    }
    if (tid == 0) atomicAdd(&ws[WS_LOSS], red[0]);

    // ---- quantized output: out[b][c][hw0+p] = cb[wk[p]][c] -----------------
    // stores coalesced (512B per c-row); cb gather L1/L2-hot.
    float* ob = out + (size_t)b * CDIM * HWSZ + hw0;
    #pragma unroll
    for (int i = 0; i < (CDIM * P) / THREADS; ++i) {   // 32 iters
        const int linear = i * THREADS + tid;          // 0..16383
        const int c = linear >> 7;
        const int p = linear & 127;
        ob[(size_t)c * HWSZ + p] = cb[(size_t)wkls[p] * CDIM + c];
    }
}

// ---- pass 2: scalars --------------------------------------------------------
__global__ __launch_bounds__(1024) void vq_final(const float* __restrict__ ws,
                                                 float* __restrict__ out) {
    __shared__ float red[1024];
    const int t = threadIdx.x;
    const unsigned int* hist = (const unsigned int*)ws + WS_HIST;
    const float p = (float)hist[t] * INV_NPOS;
    red[t] = p * logf(p + 1e-10f);
    __syncthreads();
    for (int s = 512; s > 0; s >>= 1) {
        if (t < s) red[t] += red[t + s];
        __syncthreads();
    }
    if (t == 0) {
        out[LOSS_OFF] = 1.25f * (ws[WS_LOSS] * INV_TOTAL);   // cb + 0.25*commit
        out[PERP_OFF] = expf(-red[0]);
    }
}

extern "C" void kernel_launch(void* const* d_in, const int* in_sizes, int n_in,
                              void* d_out, int out_size, void* d_ws, size_t ws_size,
                              hipStream_t stream) {
    const float* z  = (const float*)d_in[0];
    const float* cb = (const float*)d_in[1];
    float* out = (float*)d_out;
    float* ws  = (float*)d_ws;

    vq_prep <<<KCODES / 256, 256, 0, stream>>>(cb, ws);
    vq_main <<<NPOS / P,     THREADS, 0, stream>>>(z, cb, ws, out);
    vq_final<<<1,           1024, 0, stream>>>(ws, out);
}